// Round 7
// baseline (214.068 us; speedup 1.0000x reference)
//
#include <hip/hip_runtime.h>
#include <hip/hip_bf16.h>
#include <stdint.h>

// Problem: B=128, S=512, I=128, Hd=512, G=3*Hd=1536, M=B*S=65536.
//
// ALGEBRAIC FUSION (r4, kept): gi = x @ (W_ih@W_emb)^T + (W_ih@b_emb + b_ih)
// -> precompute W_fused (1536x128) + b_fused (1536), one K=128 GEMM + gates.
//
// Round 7: r6 structure, epilogue fixed.
//  wprep    : fp32-VALU mini-GEMM W_fused = W_ih@W_emb + b_fused (unchanged).
//  gru_main : x fp32 read direct -> A-frags in registers; B streamed over
//             16 h-chunks dbuf'd in LDS. Epilogue back to r5-proven LDS
//             repack + float4 stores (4 stores/lane, 256B segments) instead
//             of 16 scattered dwords. Loop barrier = s_waitcnt vmcnt(4) +
//             s_barrier: next B tile guaranteed resident, the 4 stores drain
//             one chunk later (store latency off the critical path; vmcnt
//             never 0 inside the loop).
#define M_TOT   65536
#define I_DIM   128
#define HD      512
#define HOFF    33488896   // 128*511*512, element offset of h_last in d_out
#define HROW    261632     // 511*512, per-b row stride of H

typedef __bf16 bf16x8 __attribute__((ext_vector_type(8)));
typedef float f32x4 __attribute__((ext_vector_type(4)));

// async global->LDS, 16B per lane (lane-scatter base+lane*16, m104/m108).
__device__ __forceinline__ void async_load16(const void* g, void* l) {
  __builtin_amdgcn_global_load_lds(
      (const __attribute__((address_space(1))) void*)g,
      (__attribute__((address_space(3))) void*)l, 16, 0, 0);
}

// v_rcp_f32: rel err 2^-22 — far below the 1.4e-2 abs threshold.
__device__ __forceinline__ float fastrcp(float x) {
  return __builtin_amdgcn_rcpf(x);
}
__device__ __forceinline__ float sigf(float x) {
  return fastrcp(1.0f + __expf(-x));
}
__device__ __forceinline__ float tanhfast(float x) {
  return 1.0f - 2.0f * fastrcp(__expf(2.0f * x) + 1.0f);
}

// ---------------------------------------------------------------------------
// wprep: W_fused[g,i] = sum_h wi[g,h]*wemb[h,i]  (fp32 FMA, bf16 out)
//        b_fused[g]   = b_ih[g] + sum_h wi[g,h]*b_emb[h]
// Grid 384 blocks x 256 thr; block = 4 g-rows. (unchanged from r6)
// ---------------------------------------------------------------------------
__global__ __launch_bounds__(256) void wprep(
    const float* __restrict__ wi,     // (1536,512)
    const float* __restrict__ we,     // (512,128)
    const float* __restrict__ b_emb,  // (512)
    const float* __restrict__ b_ih,   // (1536)
    __hip_bfloat16* __restrict__ wf,  // (1536,128) out
    float* __restrict__ bfu)          // (1536) out
{
  __shared__ float wis[4 * 512];      // 8 KB
  __shared__ float bes[512];          // 2 KB
  const int tid = threadIdx.x;
  const int g0  = blockIdx.x * 4;

#pragma unroll
  for (int j = 0; j < 2; ++j)
    ((float4*)wis)[j * 256 + tid] =
        ((const float4*)(wi + (size_t)g0 * HD))[j * 256 + tid];
  if (tid < 128) ((float4*)bes)[tid] = ((const float4*)b_emb)[tid];
  __syncthreads();

  const int i   = tid & 127;          // output column
  const int seg = tid >> 7;           // 0,1 -> g pair
  float a0 = 0.0f, a1 = 0.0f;
#pragma unroll 4
  for (int h = 0; h < 512; h += 4) {
    const f32x4 w0 = *(const f32x4*)&wis[(seg * 2 + 0) * 512 + h];
    const f32x4 w1 = *(const f32x4*)&wis[(seg * 2 + 1) * 512 + h];
#pragma unroll
    for (int j = 0; j < 4; ++j) {
      const float wev = we[(size_t)(h + j) * I_DIM + i];
      a0 = fmaf(w0[j], wev, a0);
      a1 = fmaf(w1[j], wev, a1);
    }
  }
  wf[(size_t)(g0 + seg * 2 + 0) * I_DIM + i] = __float2bfloat16(a0);
  wf[(size_t)(g0 + seg * 2 + 1) * I_DIM + i] = __float2bfloat16(a1);

  if (tid < 64) {
#pragma unroll
    for (int g = 0; g < 4; ++g) {
      float s = 0.0f;
#pragma unroll
      for (int h = 0; h < 8; ++h) s += wis[g * 512 + tid + h * 64] * bes[tid + h * 64];
#pragma unroll
      for (int off = 32; off; off >>= 1) s += __shfl_down(s, off);
      if (tid == 0) bfu[g0 + g] = s + b_ih[g0 + g];
    }
  }
}

// ---------------------------------------------------------------------------
// gru_main: gi[m, g*512+h] = sum_i x[m,i]*W_fused[g*512+h,i]; gate math.
// Grid = 512 blocks (128 M-rows each, ALL 512 h) = 2 blocks/CU.
// 4 waves x 32 M-rows. A: x fp32 direct -> bf16 frags af[4ks][2mi] (once).
// B: W_fused streamed over 16 h-chunks of 32 h x 3 gates (96 rows), two
// half-K [96][64] tiles per buffer, double-buffered (2x24 KB).
// LDS: B dbuf 48 KB ++ obuf 4 x 5120 B = 68.5 KB total -> 2 blocks/CU.
// Per chunk: stage next (6 loads/wave) | 24 ds_read_b128 | 48 MFMA (setprio)
// | gate math | LDS repack (stride 40) | 4 float4 stores | vmcnt(4)+s_barrier.
// ---------------------------------------------------------------------------
__device__ __forceinline__ void stage_B32(const __hip_bfloat16* __restrict__ wf,
                                          int hc, char* Bbuf,
                                          int w, int lrow, int gc) {
  const int h0 = hc * 32;
#pragma unroll
  for (int j = 0; j < 6; ++j) {
    const int idx = w * 6 + j;          // 0..23
    const int kh = idx / 12;            // K-half
    const int cr = idx % 12;            // 8-row chunk within [96]
    const int r  = cr * 8 + lrow;       // 0..95
    const int g  = r >> 5;              // gate
    const int hh = r & 31;              // h within chunk
    async_load16(wf + (size_t)(g * HD + h0 + hh) * I_DIM + kh * 64 + gc,
                 (void*)&((__hip_bfloat16*)Bbuf)[kh * 6144 + cr * 512]);
  }
}

__global__ __launch_bounds__(256, 2) void gru_main(
    const float* __restrict__ x_f,            // (65536,128) fp32 (d_in)
    const __hip_bfloat16* __restrict__ wf,    // (1536,128) bf16
    const float* __restrict__ bfu,            // (1536) fp32  b_fused
    const float* __restrict__ b_hh,           // (1536) fp32
    float* __restrict__ out)                  // H ++ h_last fp32
{
  // [0,48K): B dbuf (2 x 24 KB); [48K, +20K): obuf (4 waves x 5120 B)
  __shared__ __align__(16) char smem[69632];

  const int tid  = threadIdx.x;
  const int w    = tid >> 6;
  const int lane = tid & 63;
  const int m0 = blockIdx.x * 128;
  const int wm = w * 32;                      // wave M-offset
  const int lrow = lane >> 3;
  const int gc   = ((lane & 7) ^ lrow) * 8;   // swizzled global element offset
  const int l15 = lane & 15;
  const int q   = lane >> 4;
  const int sx  = l15 & 7;

  // issue B(0) staging first, build A-frags while the loads fly
  stage_B32(wf, 0, smem, w, lrow, gc);

  // A fragments direct from global fp32: af[ks][mi], frag = 8 contiguous k
  bf16x8 af[4][2];
#pragma unroll
  for (int mi = 0; mi < 2; ++mi) {
    const float* xp = x_f + (size_t)(m0 + wm + mi * 16 + l15) * I_DIM + q * 8;
#pragma unroll
    for (int ks = 0; ks < 4; ++ks) {
      const float4 c0 = *(const float4*)(xp + ks * 32);
      const float4 c1 = *(const float4*)(xp + ks * 32 + 4);
      bf16x8 v;
      v[0] = (__bf16)c0.x; v[1] = (__bf16)c0.y;
      v[2] = (__bf16)c0.z; v[3] = (__bf16)c0.w;
      v[4] = (__bf16)c1.x; v[5] = (__bf16)c1.y;
      v[6] = (__bf16)c1.z; v[7] = (__bf16)c1.w;
      af[ks][mi] = v;
    }
  }
  __syncthreads();   // full drain once: B(0) + A loads complete

  float* obuf = (float*)(smem + 49152 + w * 5120);  // wave-private repack
  const int srow = lane >> 3;        // 0..7
  const int scol = (lane & 7) * 4;   // 0,4,...,28

#pragma unroll 2
  for (int hc = 0; hc < 16; ++hc) {
    const __hip_bfloat16* Bs = (const __hip_bfloat16*)(smem + (hc & 1) * 24576);
    if (hc < 15)
      stage_B32(wf, hc + 1, smem + ((hc + 1) & 1) * 24576, w, lrow, gc);
    __builtin_amdgcn_sched_barrier(0);        // pin stage issue at chunk top

    f32x4 acc[3][2][2];
#pragma unroll
    for (int g = 0; g < 3; ++g)
#pragma unroll
      for (int mi = 0; mi < 2; ++mi)
#pragma unroll
        for (int ni = 0; ni < 2; ++ni) acc[g][mi][ni] = (f32x4)0.0f;

    __builtin_amdgcn_s_setprio(1);
#pragma unroll
    for (int g = 0; g < 3; ++g)
#pragma unroll
      for (int ks = 0; ks < 4; ++ks) {
        const int half = ks >> 1;
        const int s = (((ks & 1) * 4 + q) ^ sx) * 8;
#pragma unroll
        for (int ni = 0; ni < 2; ++ni) {
          const bf16x8 bv =
              *(const bf16x8*)&Bs[half * 6144 + (g * 32 + ni * 16 + l15) * 64 + s];
#pragma unroll
          for (int mi = 0; mi < 2; ++mi)
            acc[g][mi][ni] = __builtin_amdgcn_mfma_f32_16x16x32_bf16(
                af[ks][mi], bv, acc[g][mi][ni], 0, 0, 0);
        }
      }
    __builtin_amdgcn_s_setprio(0);

    // gate math + wave-private LDS repack (stride 40 floats) + float4 stores
    const int h0 = hc * 32;
#pragma unroll
    for (int ni = 0; ni < 2; ++ni) {
      const int col = h0 + ni * 16 + l15;
      const float br = bfu[col] + b_hh[col];
      const float bz = bfu[HD + col] + b_hh[HD + col];
      const float bn = bfu[2 * HD + col];
      const float bhn = b_hh[2 * HD + col];
#pragma unroll
      for (int mi = 0; mi < 2; ++mi) {
#pragma unroll
        for (int r = 0; r < 4; ++r) {
          const float rr = sigf(acc[0][mi][ni][r] + br);
          const float zz = sigf(acc[1][mi][ni][r] + bz);
          const float nn = tanhfast(acc[2][mi][ni][r] + bn + rr * bhn);
          obuf[(mi * 16 + q * 4 + r) * 40 + ni * 16 + l15] = (1.0f - zz) * nn;
        }
      }
    }
    // wave-private obuf: same-wave LDS ops are in-order; compiler lgkmcnt
    // orders write->read (r5-verified pattern).
#pragma unroll
    for (int i = 0; i < 4; ++i) {
      const int row = i * 8 + srow;           // m_local 0..31
      const float4 v = *(const float4*)&obuf[row * 40 + scol];
      const int m = m0 + wm + row;
      const int b = m >> 9;                   // m / 512
      const int s = m & 511;                  // m % 512
      float* dst = (s < 511)
          ? out + (size_t)b * HROW + (size_t)s * HD + h0 + scol
          : out + (size_t)HOFF + (size_t)b * HD + h0 + scol;
      *(float4*)dst = v;
    }

    if (hc < 15) {
      // FIFO this chunk: 6 stage loads, then 4 stores. vmcnt(4) retires the
      // 6 loads (next B tile resident) + any older stores; this chunk's 4
      // stores drain during the NEXT chunk — store latency off the loop path.
      asm volatile("s_waitcnt vmcnt(4)" ::: "memory");
      __builtin_amdgcn_sched_barrier(0);
      __builtin_amdgcn_s_barrier();
    }
  }
}

extern "C" void kernel_launch(void* const* d_in, const int* in_sizes, int n_in,
                              void* d_out, int out_size, void* d_ws, size_t ws_size,
                              hipStream_t stream) {
  const float* x_f     = (const float*)d_in[0];   // (128,512,128)
  const float* w_emb_f = (const float*)d_in[1];   // (512,128)
  const float* b_emb   = (const float*)d_in[2];   // (512)
  const float* w_ih_f  = (const float*)d_in[3];   // (1536,512)
  const float* b_ih    = (const float*)d_in[4];   // (1536)
  const float* b_hh    = (const float*)d_in[5];   // (1536)
  float* out = (float*)d_out;

  // ws layout (bytes):
  //   [0, 384Ki)        W_fused bf16 (1536*128*2)
  //   [393216, +6Ki)    b_fused f32  (1536*4)
  char* ws = (char*)d_ws;
  __hip_bfloat16* wf_bf = (__hip_bfloat16*)(ws);
  float*          b_fu  = (float*)(ws + 393216);

  wprep<<<384, 256, 0, stream>>>(w_ih_f, w_emb_f, b_emb, b_ih, wf_bf, b_fu);

  gru_main<<<M_TOT / 128, 256, 0, stream>>>(x_f, wf_bf, b_fu, b_hh, out);
}

// Round 8
// 211.291 us; speedup vs baseline: 1.0131x; 1.0131x over previous
//
#include <hip/hip_runtime.h>
#include <hip/hip_bf16.h>
#include <stdint.h>

// Problem: B=128, S=512, I=128, Hd=512, G=3*Hd=1536, M=B*S=65536.
//
// ALGEBRAIC FUSION (r4, kept): gi = x @ (W_ih@W_emb)^T + (W_ih@b_emb + b_ih)
// -> precompute W_fused (1536x128) + b_fused (1536), one K=128 GEMM + gates.
//
// Round 8: gru_main wave decomposition 4Mx1h -> 2Mx2h.
//   Wave = 64M x 16h x 3g. B ds_reads per chunk halve (24 -> 12 b128,
//   1 read : 4 MFMA), bias loads halve; A-frags af[4ks][4mi] (64 VGPR,
//   built once from global fp32). Everything else = r7 (stage_B32 via
//   global_load_lds, 16 h-chunks dbuf'd, vmcnt(4)+s_barrier loop, LDS
//   repack + float4 stores).
#define M_TOT   65536
#define I_DIM   128
#define HD      512
#define HOFF    33488896   // 128*511*512, element offset of h_last in d_out
#define HROW    261632     // 511*512, per-b row stride of H

typedef __bf16 bf16x8 __attribute__((ext_vector_type(8)));
typedef float f32x4 __attribute__((ext_vector_type(4)));

// async global->LDS, 16B per lane (lane-scatter base+lane*16, m104/m108).
__device__ __forceinline__ void async_load16(const void* g, void* l) {
  __builtin_amdgcn_global_load_lds(
      (const __attribute__((address_space(1))) void*)g,
      (__attribute__((address_space(3))) void*)l, 16, 0, 0);
}

// v_rcp_f32: rel err 2^-22 — far below the 1.4e-2 abs threshold.
__device__ __forceinline__ float fastrcp(float x) {
  return __builtin_amdgcn_rcpf(x);
}
__device__ __forceinline__ float sigf(float x) {
  return fastrcp(1.0f + __expf(-x));
}
__device__ __forceinline__ float tanhfast(float x) {
  return 1.0f - 2.0f * fastrcp(__expf(2.0f * x) + 1.0f);
}

// ---------------------------------------------------------------------------
// wprep: W_fused[g,i] = sum_h wi[g,h]*wemb[h,i]  (fp32 FMA, bf16 out)
//        b_fused[g]   = b_ih[g] + sum_h wi[g,h]*b_emb[h]
// Grid 384 blocks x 256 thr; block = 4 g-rows. (unchanged from r6)
// ---------------------------------------------------------------------------
__global__ __launch_bounds__(256) void wprep(
    const float* __restrict__ wi,     // (1536,512)
    const float* __restrict__ we,     // (512,128)
    const float* __restrict__ b_emb,  // (512)
    const float* __restrict__ b_ih,   // (1536)
    __hip_bfloat16* __restrict__ wf,  // (1536,128) out
    float* __restrict__ bfu)          // (1536) out
{
  __shared__ float wis[4 * 512];      // 8 KB
  __shared__ float bes[512];          // 2 KB
  const int tid = threadIdx.x;
  const int g0  = blockIdx.x * 4;

#pragma unroll
  for (int j = 0; j < 2; ++j)
    ((float4*)wis)[j * 256 + tid] =
        ((const float4*)(wi + (size_t)g0 * HD))[j * 256 + tid];
  if (tid < 128) ((float4*)bes)[tid] = ((const float4*)b_emb)[tid];
  __syncthreads();

  const int i   = tid & 127;          // output column
  const int seg = tid >> 7;           // 0,1 -> g pair
  float a0 = 0.0f, a1 = 0.0f;
#pragma unroll 4
  for (int h = 0; h < 512; h += 4) {
    const f32x4 w0 = *(const f32x4*)&wis[(seg * 2 + 0) * 512 + h];
    const f32x4 w1 = *(const f32x4*)&wis[(seg * 2 + 1) * 512 + h];
#pragma unroll
    for (int j = 0; j < 4; ++j) {
      const float wev = we[(size_t)(h + j) * I_DIM + i];
      a0 = fmaf(w0[j], wev, a0);
      a1 = fmaf(w1[j], wev, a1);
    }
  }
  wf[(size_t)(g0 + seg * 2 + 0) * I_DIM + i] = __float2bfloat16(a0);
  wf[(size_t)(g0 + seg * 2 + 1) * I_DIM + i] = __float2bfloat16(a1);

  if (tid < 64) {
#pragma unroll
    for (int g = 0; g < 4; ++g) {
      float s = 0.0f;
#pragma unroll
      for (int h = 0; h < 8; ++h) s += wis[g * 512 + tid + h * 64] * bes[tid + h * 64];
#pragma unroll
      for (int off = 32; off; off >>= 1) s += __shfl_down(s, off);
      if (tid == 0) bfu[g0 + g] = s + b_ih[g0 + g];
    }
  }
}

// ---------------------------------------------------------------------------
// gru_main: gi[m, g*512+h] = sum_i x[m,i]*W_fused[g*512+h,i]; gate math.
// Grid = 512 blocks (128 M-rows each, ALL 512 h) = 2 blocks/CU.
// 4 waves as 2M x 2h: wave = 64M x 16h x 3 gates.
//   A: x fp32 direct -> bf16 frags af[4ks][4mi] (64 VGPR, once).
//   B: W_fused streamed over 16 h-chunks of 32 h x 3 gates (96 rows), two
//      half-K [96][64] tiles per buffer, double-buffered (2x24 KB).
//   Per chunk per wave: stage 6 | 12 ds_read_b128 (1:4 with 48 MFMA,
//   setprio) | gate math (16 outputs/lane, 1 h-col) | LDS repack | 4 float4
//   stores | vmcnt(4)+s_barrier (stores drain next chunk, vmcnt never 0).
// LDS: B dbuf 48 KB ++ obuf 4 x 5120 B = 68 KB -> 2 blocks/CU.
// ---------------------------------------------------------------------------
__device__ __forceinline__ void stage_B32(const __hip_bfloat16* __restrict__ wf,
                                          int hc, char* Bbuf,
                                          int w, int lrow, int gc) {
  const int h0 = hc * 32;
#pragma unroll
  for (int j = 0; j < 6; ++j) {
    const int idx = w * 6 + j;          // 0..23
    const int kh = idx / 12;            // K-half
    const int cr = idx % 12;            // 8-row chunk within [96]
    const int r  = cr * 8 + lrow;       // 0..95
    const int g  = r >> 5;              // gate
    const int hh = r & 31;              // h within chunk
    async_load16(wf + (size_t)(g * HD + h0 + hh) * I_DIM + kh * 64 + gc,
                 (void*)&((__hip_bfloat16*)Bbuf)[kh * 6144 + cr * 512]);
  }
}

__global__ __launch_bounds__(256, 2) void gru_main(
    const float* __restrict__ x_f,            // (65536,128) fp32 (d_in)
    const __hip_bfloat16* __restrict__ wf,    // (1536,128) bf16
    const float* __restrict__ bfu,            // (1536) fp32  b_fused
    const float* __restrict__ b_hh,           // (1536) fp32
    float* __restrict__ out)                  // H ++ h_last fp32
{
  // [0,48K): B dbuf (2 x 24 KB); [48K, +20K): obuf (4 waves x 5120 B)
  __shared__ __align__(16) char smem[69632];

  const int tid  = threadIdx.x;
  const int w    = tid >> 6;
  const int lane = tid & 63;
  const int m0 = blockIdx.x * 128;
  const int wmb = (w >> 1) * 64;              // wave M-offset: 0, 64
  const int wn  = (w & 1) * 16;               // wave h-offset within chunk
  const int lrow = lane >> 3;
  const int gc   = ((lane & 7) ^ lrow) * 8;   // swizzled global element offset
  const int l15 = lane & 15;
  const int q   = lane >> 4;
  const int sx  = l15 & 7;                    // == (wn+l15)&7 since wn%8==0... wn=16: (16+l15)&7 = l15&7 ✓

  // issue B(0) staging first, build A-frags while the loads fly
  stage_B32(wf, 0, smem, w, lrow, gc);

  // A fragments direct from global fp32: af[ks][mi], frag = 8 contiguous k
  bf16x8 af[4][4];
#pragma unroll
  for (int mi = 0; mi < 4; ++mi) {
    const float* xp = x_f + (size_t)(m0 + wmb + mi * 16 + l15) * I_DIM + q * 8;
#pragma unroll
    for (int ks = 0; ks < 4; ++ks) {
      const float4 c0 = *(const float4*)(xp + ks * 32);
      const float4 c1 = *(const float4*)(xp + ks * 32 + 4);
      bf16x8 v;
      v[0] = (__bf16)c0.x; v[1] = (__bf16)c0.y;
      v[2] = (__bf16)c0.z; v[3] = (__bf16)c0.w;
      v[4] = (__bf16)c1.x; v[5] = (__bf16)c1.y;
      v[6] = (__bf16)c1.z; v[7] = (__bf16)c1.w;
      af[ks][mi] = v;
    }
  }
  __syncthreads();   // full drain once: B(0) + A loads complete

  float* obuf = (float*)(smem + 49152 + w * 5120);  // wave-private repack
  const int srow = lane >> 2;        // 0..15
  const int scol = (lane & 3) * 4;   // 0,4,8,12

#pragma unroll 2
  for (int hc = 0; hc < 16; ++hc) {
    const __hip_bfloat16* Bs = (const __hip_bfloat16*)(smem + (hc & 1) * 24576);
    if (hc < 15)
      stage_B32(wf, hc + 1, smem + ((hc + 1) & 1) * 24576, w, lrow, gc);
    __builtin_amdgcn_sched_barrier(0);        // pin stage issue at chunk top

    f32x4 acc[3][4];
#pragma unroll
    for (int g = 0; g < 3; ++g)
#pragma unroll
      for (int mi = 0; mi < 4; ++mi) acc[g][mi] = (f32x4)0.0f;

    __builtin_amdgcn_s_setprio(1);
#pragma unroll
    for (int g = 0; g < 3; ++g)
#pragma unroll
      for (int ks = 0; ks < 4; ++ks) {
        const int half = ks >> 1;
        const int s = (((ks & 1) * 4 + q) ^ sx) * 8;
        const bf16x8 bv =
            *(const bf16x8*)&Bs[half * 6144 + (g * 32 + wn + l15) * 64 + s];
#pragma unroll
        for (int mi = 0; mi < 4; ++mi)
          acc[g][mi] = __builtin_amdgcn_mfma_f32_16x16x32_bf16(
              af[ks][mi], bv, acc[g][mi], 0, 0, 0);
      }
    __builtin_amdgcn_s_setprio(0);

    // gate math: each lane owns ONE h-col (col = h0+wn+l15), 16 M-rows.
    const int h0 = hc * 32;
    const int col = h0 + wn + l15;
    const float br = bfu[col] + b_hh[col];
    const float bz = bfu[HD + col] + b_hh[HD + col];
    const float bn = bfu[2 * HD + col];
    const float bhn = b_hh[2 * HD + col];
#pragma unroll
    for (int mi = 0; mi < 4; ++mi) {
#pragma unroll
      for (int r = 0; r < 4; ++r) {
        const float rr = sigf(acc[0][mi][r] + br);
        const float zz = sigf(acc[1][mi][r] + bz);
        const float nn = tanhfast(acc[2][mi][r] + bn + rr * bhn);
        // wave tile repack: row = mi*16 + q*4 + r (0..63), col l15, stride 20
        obuf[(mi * 16 + q * 4 + r) * 20 + l15] = (1.0f - zz) * nn;
      }
    }
    // wave-private obuf: same-wave LDS ops in-order; compiler lgkmcnt
    // orders write->read (r5/r7-verified pattern).
#pragma unroll
    for (int i = 0; i < 4; ++i) {
      const int row = i * 16 + srow;          // m_local 0..63
      const float4 v = *(const float4*)&obuf[row * 20 + scol];
      const int m = m0 + wmb + row;
      const int b = m >> 9;                   // m / 512
      const int s = m & 511;                  // m % 512
      float* dst = (s < 511)
          ? out + (size_t)b * HROW + (size_t)s * HD + h0 + wn + scol
          : out + (size_t)HOFF + (size_t)b * HD + h0 + wn + scol;
      *(float4*)dst = v;
    }

    if (hc < 15) {
      // FIFO this chunk: 6 stage loads, then 4 stores. vmcnt(4) retires the
      // 6 loads (next B tile resident); this chunk's 4 stores drain during
      // the NEXT chunk — store latency off the loop path; vmcnt never 0.
      asm volatile("s_waitcnt vmcnt(4)" ::: "memory");
      __builtin_amdgcn_sched_barrier(0);
      __builtin_amdgcn_s_barrier();
    }
  }
}

extern "C" void kernel_launch(void* const* d_in, const int* in_sizes, int n_in,
                              void* d_out, int out_size, void* d_ws, size_t ws_size,
                              hipStream_t stream) {
  const float* x_f     = (const float*)d_in[0];   // (128,512,128)
  const float* w_emb_f = (const float*)d_in[1];   // (512,128)
  const float* b_emb   = (const float*)d_in[2];   // (512)
  const float* w_ih_f  = (const float*)d_in[3];   // (1536,512)
  const float* b_ih    = (const float*)d_in[4];   // (1536)
  const float* b_hh    = (const float*)d_in[5];   // (1536)
  float* out = (float*)d_out;

  // ws layout (bytes):
  //   [0, 384Ki)        W_fused bf16 (1536*128*2)
  //   [393216, +6Ki)    b_fused f32  (1536*4)
  char* ws = (char*)d_ws;
  __hip_bfloat16* wf_bf = (__hip_bfloat16*)(ws);
  float*          b_fu  = (float*)(ws + 393216);

  wprep<<<384, 256, 0, stream>>>(w_ih_f, w_emb_f, b_emb, b_ih, wf_bf, b_fu);

  gru_main<<<M_TOT / 128, 256, 0, stream>>>(x_f, wf_bf, b_fu, b_hh, out);
}